// Round 8
// baseline (125.342 us; speedup 1.0000x reference)
//
#include <hip/hip_runtime.h>

#define NUM_HEADS 16
#define HEAD_DIM  128
#define SEQ       2048

typedef __attribute__((ext_vector_type(8))) unsigned short us8;
typedef __attribute__((ext_vector_type(8))) __bf16 bf16x8;
typedef __attribute__((ext_vector_type(4))) float f32x4;
typedef __attribute__((ext_vector_type(16))) float f32x16;
typedef __attribute__((ext_vector_type(4))) unsigned u32x4;

static __device__ inline unsigned short f2bf(float x) {   // RNE
    union { float f; unsigned u; } v; v.f = x;
    unsigned r = v.u + 0x7FFFu + ((v.u >> 16) & 1u);
    return (unsigned short)(r >> 16);
}
static __device__ inline float bf2f(unsigned short h) {
    union { float f; unsigned u; } v; v.u = ((unsigned)h) << 16;
    return v.f;
}
static __device__ inline unsigned pk2bf(float a, float b) {
    return (unsigned)f2bf(a) | ((unsigned)f2bf(b) << 16);
}
static __device__ inline float fast_exp2(float x) {
#if __has_builtin(__builtin_amdgcn_exp2f)
    return __builtin_amdgcn_exp2f(x);
#else
    return exp2f(x);
#endif
}
static __device__ inline f32x16 mfma32(us8 a, us8 b, f32x16 c) {
    return __builtin_amdgcn_mfma_f32_32x32x16_bf16(
        __builtin_bit_cast(bf16x8, a), __builtin_bit_cast(bf16x8, b), c, 0, 0, 0);
}

// ---------- pre-pass: K -> bf16 row-major; V -> bf16 transposed per 64-tile ----------
__global__ __launch_bounds__(256)
void prep_kv(const float* __restrict__ K, const float* __restrict__ V,
             unsigned short* __restrict__ Kbf, unsigned short* __restrict__ Vtb)
{
    const int bx = (int)blockIdx.x, t = (int)threadIdx.x;
    __shared__ __align__(16) float Ls[64][130];
    if (bx < 512) {
        const size_t base = ((size_t)bx * 256 + t) * 8;
        float x[8];
        *(float4*)&x[0] = *(const float4*)(K + base);
        *(float4*)&x[4] = *(const float4*)(K + base + 4);
        u32x4 pk;
        #pragma unroll
        for (int j = 0; j < 4; ++j) pk[j] = pk2bf(x[2*j], x[2*j+1]);
        *(us8*)(Kbf + base) = __builtin_bit_cast(us8, pk);
    } else {
        const int b2 = bx - 512, kvh = b2 >> 5, tile = b2 & 31;
        const float* vb = V + ((size_t)kvh * SEQ + tile * 64) * HEAD_DIM;
        #pragma unroll
        for (int i = 0; i < 8; ++i) {
            const int idx = t + i * 256;
            const int r = idx >> 5, c4 = idx & 31;
            *(float4*)&Ls[r][c4 * 4] = *(const float4*)(vb + (size_t)r * HEAD_DIM + c4 * 4);
        }
        __syncthreads();
        const int d = t & 127, kh = t >> 7;
        unsigned pk[16];
        #pragma unroll
        for (int j = 0; j < 16; ++j)
            pk[j] = pk2bf(Ls[kh * 32 + 2*j][d], Ls[kh * 32 + 2*j + 1][d]);
        unsigned short* dst = Vtb + ((size_t)(kvh * 32 + tile) * 128 + d) * 64 + kh * 32;
        #pragma unroll
        for (int blk = 0; blk < 4; ++blk)
            *(us8*)(dst + blk * 8) = *(us8*)&pk[blk * 4];
    }
}

// ---------- main: 32x32x16 MFMA, register-P, equal-length persistent blocks ----------
// smem: K dbuf 2x16384 | Vt dbuf 2x16384 = 65536 B (+512 rsb) -> 2 blocks/CU
#define KB0 0
#define KB1 16384
#define VB0 32768
#define VB1 49152

__global__ __launch_bounds__(256, 2)
void diff_attn_mfma6(const float* __restrict__ Q,
                     const unsigned short* __restrict__ Kbf,
                     const unsigned short* __restrict__ Vtb,
                     float* __restrict__ Out)
{
    __shared__ __align__(16) unsigned char smem[65536];
    __shared__ float rsb[2][2][32];

    const int t   = (int)threadIdx.x;
    const int wv  = t >> 6;
    const int ln  = t & 63;
    const int mat = wv >> 1;        // 0: softmax1 (Q/K dims 0..63), 1: softmax2 (64..127)
    const int kh  = wv & 1;         // k-half of the 64-k tile this wave reduces
    const int q   = ln & 31;        // q-col (C/B layout n) and A-layout m
    const int H   = ln >> 5;        // lane half

    // grid 512 = 16 h x 32 pair-slots; block does q-tiles (idx, 63-idx) SEQUENTIALLY
    // -> every block runs exactly 33 iterations (equal duration, 2 blocks/CU sustained)
    const int bx   = (int)blockIdx.x;
    const int h    = bx & 15;
    const int idx  = bx >> 4;                 // 0..31
    const int qtA  = idx, qtB = 63 - idx;
    const int nktA = (qtA >> 1) + 1;          // 33 - nktB
    const int kvh  = h >> 2;

    const unsigned short* Kt0 = Kbf + (size_t)kvh * SEQ * HEAD_DIM;
    const unsigned short* Vt0 = Vtb + (size_t)kvh * 32 * 128 * 64;

    const float qscale = 0.125f * 1.44269504088896340736f;  // 1/8 * log2(e)

    us8 qhi[4], qlo[4];
    auto loadQ = [&](int q0c) {
        const float* qr = Q + ((size_t)h * SEQ + q0c + q) * HEAD_DIM + mat * 64;
        #pragma unroll
        for (int ds = 0; ds < 4; ++ds) {
            const int d0 = ds * 16 + H * 8;
            float x[8];
            *(float4*)&x[0] = *(const float4*)(qr + d0);
            *(float4*)&x[4] = *(const float4*)(qr + d0 + 4);
            us8 hi8, lo8;
            #pragma unroll
            for (int j = 0; j < 8; ++j) {
                float xs = x[j] * qscale;
                unsigned short hb = f2bf(xs);
                hi8[j] = hb;
                lo8[j] = f2bf(xs - bf2f(hb));
            }
            qhi[ds] = hi8; qlo[ds] = lo8;
        }
    };

    f32x16 o[4];                   // O^T partial: dim=db*32+(reg&3)+8*(reg>>2)+4H, q-col=q
    f32x4 rsv;                     // row-sum partials (this wave's kh half)
    #pragma unroll
    for (int i = 0; i < 4; ++i) o[i] = (f32x16)0.f;
    rsv = (f32x4)0.f;

    // async staging of k-tile kt into dbuf parity par
    auto issue = [&](int kt, int par) {
        unsigned char* kb = smem + (par ? KB1 : KB0);
        unsigned char* vb = smem + (par ? VB1 : VB0);
        #pragma unroll
        for (int i = 0; i < 4; ++i) {
            const int L = i * 256 + t;
            const int r = L >> 4, g = (L & 15) ^ (r & 15);
            const unsigned short* gp = Kt0 + (size_t)(kt * 64 + r) * 128 + g * 8;
            __builtin_amdgcn_global_load_lds(
                (const __attribute__((address_space(1))) unsigned*)gp,
                (__attribute__((address_space(3))) unsigned*)(kb + (size_t)(i * 256 + wv * 64) * 16),
                16, 0, 0);
        }
        #pragma unroll
        for (int i = 0; i < 4; ++i) {
            const int L = i * 256 + t;
            const int r = L >> 3, g = (L & 7) ^ (r & 7);
            const unsigned short* gp = Vt0 + (size_t)(kt * 128 + r) * 64 + g * 8;
            __builtin_amdgcn_global_load_lds(
                (const __attribute__((address_space(1))) unsigned*)gp,
                (__attribute__((address_space(3))) unsigned*)(vb + (size_t)(i * 256 + wv * 64) * 16),
                16, 0, 0);
        }
    };

    // epilogue for one q-tile: combine kh-partials + mats via free dbuf half, store
    auto epilogue = [&](int q0c, int epar) {
        __syncthreads();   // all compute done; free dbuf half safe to reuse
        float rsc = (rsv[0] + rsv[1]) + (rsv[2] + rsv[3]);
        rsc += __shfl_xor(rsc, 32, 64);
        if (ln < 32) rsb[mat][kh][ln] = rsc;
        float* cbK = (float*)(smem + (epar ? KB1 : KB0));
        float* cbV = (float*)(smem + (epar ? VB1 : VB0));
        float* cbM = mat ? cbV : cbK;
        if (kh == 1) {     // write raw partials (xor-swizzled 16B chunks)
            #pragma unroll
            for (int db = 0; db < 4; ++db)
                #pragma unroll
                for (int i = 0; i < 4; ++i) {
                    f32x4 v = { o[db][i*4+0], o[db][i*4+1], o[db][i*4+2], o[db][i*4+3] };
                    *(f32x4*)(cbM + q * 128 + ((((db<<3)+(i<<1)+H) ^ q) << 2)) = v;
                }
        }
        __syncthreads();
        if (kh == 0) {     // sum kh halves, normalize; mat1 writes back
            const float l = rsb[mat][0][q] + rsb[mat][1][q];
            const float a = mat ? (0.16f / l) : (0.2f / l);
            #pragma unroll
            for (int db = 0; db < 4; ++db)
                #pragma unroll
                for (int i = 0; i < 4; ++i) {
                    f32x4 v = *(f32x4*)(cbM + q * 128 + ((((db<<3)+(i<<1)+H) ^ q) << 2));
                    #pragma unroll
                    for (int jj = 0; jj < 4; ++jj)
                        o[db][i*4+jj] = (o[db][i*4+jj] + v[jj]) * a;
                }
            if (mat == 1) {
                #pragma unroll
                for (int db = 0; db < 4; ++db)
                    #pragma unroll
                    for (int i = 0; i < 4; ++i) {
                        f32x4 v = { o[db][i*4+0], o[db][i*4+1], o[db][i*4+2], o[db][i*4+3] };
                        *(f32x4*)(cbV + q * 128 + ((((db<<3)+(i<<1)+H) ^ q) << 2)) = v;
                    }
            }
        }
        __syncthreads();
        if (wv == 0) {     // mat0/kh0: final = O1n - O2n, store
            float* ob = Out + ((size_t)h * SEQ + q0c + q) * HEAD_DIM;
            #pragma unroll
            for (int db = 0; db < 4; ++db)
                #pragma unroll
                for (int i = 0; i < 4; ++i) {
                    f32x4 v = *(f32x4*)(cbV + q * 128 + ((((db<<3)+(i<<1)+H) ^ q) << 2));
                    float4 r;
                    r.x = o[db][i*4+0] - v[0];
                    r.y = o[db][i*4+1] - v[1];
                    r.z = o[db][i*4+2] - v[2];
                    r.w = o[db][i*4+3] - v[3];
                    *(float4*)(ob + db * 32 + 8 * i + 4 * H) = r;
                }
        }
    };

    int q0 = qtA * 32, qt_cur = qtA;
    loadQ(q0);
    issue(0, 0);

    for (int j = 0; j < 33; ++j) {
        if (j == nktA) {                       // q-tile boundary
            epilogue(q0, (nktA - 1) & 1);
            q0 = qtB * 32; qt_cur = qtB;
            loadQ(q0);
            #pragma unroll
            for (int i = 0; i < 4; ++i) o[i] = (f32x16)0.f;
            rsv = (f32x4)0.f;
        }
        const int cur = j & 1;
        __syncthreads();                       // buf[cur] ready; prev reads done
        if (j + 1 < 33) issue((j + 1 < nktA) ? j + 1 : j + 1 - nktA, cur ^ 1);

        const int kt = (j < nktA) ? j : j - nktA;
        const unsigned char* kbase = smem + (cur ? KB1 : KB0);
        const unsigned char* vbase = smem + (cur ? VB1 : VB0);
        const bool diag  = (j == nktA - 1) || (j == 32);
        const int  qpar  = qt_cur & 1;
        const bool skipw = diag && (qpar == 0) && (kh == 1);   // fully-masked half
        const bool triw  = diag && (kh == qpar);               // triangular half

        if (!skipw) {
            // ---- scores S^T[kh-rows][q] = K . Q^T ----
            f32x16 s = (f32x16)0.f;
            const int krow = kh * 32 + q;
            #pragma unroll
            for (int ds = 0; ds < 4; ++ds) {
                us8 ak = *(const us8*)(kbase +
                          ((krow << 4) + ((mat * 8 + ds * 2 + H) ^ (krow & 15))) * 16);
                s = mfma32(ak, qhi[ds], s);
                s = mfma32(ak, qlo[ds], s);
            }
            // ---- exp2 + truncate to bf16 (denominator from quantized P) ----
            unsigned c[16];
            if (triw) {
                const int kg0 = kt * 64 + kh * 32 + 4 * H;
                const int qg  = q0 + q;
                #pragma unroll
                for (int r = 0; r < 16; ++r) {
                    const int kg = kg0 + (r & 3) + ((r >> 2) << 3);
                    float e = (kg <= qg) ? fast_exp2(s[r]) : 0.f;
                    c[r] = __builtin_bit_cast(unsigned, e) & 0xffff0000u;
                    rsv[r & 3] += __builtin_bit_cast(float, c[r]);
                }
            } else {
                #pragma unroll
                for (int r = 0; r < 16; ++r) {
                    float e = fast_exp2(s[r]);
                    c[r] = __builtin_bit_cast(unsigned, e) & 0xffff0000u;
                    rsv[r & 3] += __builtin_bit_cast(float, c[r]);
                }
            }
            // ---- P C-frag -> B-frag in registers (lane^32 swap), then PV ----
            #pragma unroll
            for (int ks = 0; ks < 2; ++ks) {
                const unsigned pA = (c[8*ks+0] >> 16) | c[8*ks+1];
                const unsigned pB = (c[8*ks+2] >> 16) | c[8*ks+3];
                const unsigned pC = (c[8*ks+4] >> 16) | c[8*ks+5];
                const unsigned pD = (c[8*ks+6] >> 16) | c[8*ks+7];
                const unsigned x1 = H ? pA : pC;
                const unsigned x2 = H ? pB : pD;
                const unsigned t1 = (unsigned)__shfl_xor((int)x1, 32, 64);
                const unsigned t2 = (unsigned)__shfl_xor((int)x2, 32, 64);
                u32x4 bw;
                bw[0] = H ? t1 : pA;
                bw[1] = H ? t2 : pB;
                bw[2] = H ? pC : t1;
                bw[3] = H ? pD : t2;
                const us8 bp = __builtin_bit_cast(us8, bw);
                const int gb = kh * 4 + ks * 2 + H;
                #pragma unroll
                for (int db = 0; db < 4; ++db) {
                    const int r = db * 32 + q;
                    us8 av = *(const us8*)(vbase + ((r << 3) + (gb ^ (r & 7))) * 16);
                    o[db] = mfma32(av, bp, o[db]);
                }
            }
        }
    }

    epilogue(q0, 0);
}

extern "C" void kernel_launch(void* const* d_in, const int* in_sizes, int n_in,
                              void* d_out, int out_size, void* d_ws, size_t ws_size,
                              hipStream_t stream) {
    const float* Q = (const float*)d_in[0];
    const float* K = (const float*)d_in[1];
    const float* V = (const float*)d_in[2];
    float* Out = (float*)d_out;

    unsigned short* Kbf = (unsigned short*)d_ws;             // 2 MB
    unsigned short* Vtb = Kbf + (size_t)4 * SEQ * HEAD_DIM;  // 2 MB

    prep_kv<<<640, 256, 0, stream>>>(K, V, Kbf, Vtb);
    diff_attn_mfma6<<<512, 256, 0, stream>>>(Q, Kbf, Vtb, Out);
}

// Round 9
// 116.755 us; speedup vs baseline: 1.0735x; 1.0735x over previous
//
#include <hip/hip_runtime.h>

#define NUM_HEADS 16
#define HEAD_DIM  128
#define SEQ       2048
#define KT_STRIDE 8192   // bf16 elems per k-tile group in KF/VF (16 chunks * 512)

typedef __attribute__((ext_vector_type(8))) unsigned short us8;
typedef __attribute__((ext_vector_type(8))) __bf16 bf16x8;
typedef __attribute__((ext_vector_type(4))) float f32x4;
typedef __attribute__((ext_vector_type(16))) float f32x16;
typedef __attribute__((ext_vector_type(4))) unsigned u32x4;

static __device__ inline unsigned short f2bf(float x) {   // RNE
    union { float f; unsigned u; } v; v.f = x;
    unsigned r = v.u + 0x7FFFu + ((v.u >> 16) & 1u);
    return (unsigned short)(r >> 16);
}
static __device__ inline float bf2f(unsigned short h) {
    union { float f; unsigned u; } v; v.u = ((unsigned)h) << 16;
    return v.f;
}
static __device__ inline unsigned pk2bf(float a, float b) {
    return (unsigned)f2bf(a) | ((unsigned)f2bf(b) << 16);
}
static __device__ inline float fast_exp2(float x) {
#if __has_builtin(__builtin_amdgcn_exp2f)
    return __builtin_amdgcn_exp2f(x);
#else
    return exp2f(x);
#endif
}
static __device__ inline f32x16 mfma32(us8 a, us8 b, f32x16 c) {
    return __builtin_amdgcn_mfma_f32_32x32x16_bf16(
        __builtin_bit_cast(bf16x8, a), __builtin_bit_cast(bf16x8, b), c, 0, 0, 0);
}

// ---------- pre-pass: write K and V^T in exact 32x32x16 A-fragment order ----------
// KF[kvh][kt][kh][mat][ds][lane64][8]: elem = K[kvh][kt*64+kh*32+(lane&31)][mat*64+ds*16+(lane>>5)*8+j]
// VF[kvh][kt][kh][ks][db][lane64][8]: elem = V[kvh][kt*64+kh*32+ks*16+(lane>>5)*8+j][db*32+(lane&31)]
__global__ __launch_bounds__(256)
void prep_frag(const float* __restrict__ K, const float* __restrict__ V,
               unsigned short* __restrict__ KF, unsigned short* __restrict__ VF)
{
    const int bx  = (int)blockIdx.x, t = (int)threadIdx.x;
    const int which = bx & 1, kt = (bx >> 1) & 31, kvh = bx >> 6;
    __shared__ __align__(16) float Ls[64][132];

    const float* src = (which ? V : K) + ((size_t)kvh * SEQ + kt * 64) * HEAD_DIM;
    #pragma unroll
    for (int i = 0; i < 8; ++i) {
        const int idx = t + i * 256;
        const int r = idx >> 5, c4 = idx & 31;
        *(float4*)&Ls[r][c4 * 4] = *(const float4*)(src + (size_t)r * HEAD_DIM + c4 * 4);
    }
    __syncthreads();

    if (!which) {  // K fragments
        #pragma unroll
        for (int i = 0; i < 4; ++i) {
            const int c = t + i * 256;              // 0..1023
            const int lane = c & 63, ds = (c >> 6) & 3, mat = (c >> 8) & 1, kh = c >> 9;
            const int H = lane >> 5;
            const int row = kh * 32 + (lane & 31);
            const int dim = mat * 64 + ds * 16 + H * 8;
            u32x4 pk;
            #pragma unroll
            for (int jj = 0; jj < 4; ++jj)
                pk[jj] = pk2bf(Ls[row][dim + 2*jj], Ls[row][dim + 2*jj + 1]);
            *(us8*)(KF + ((size_t)(kvh * 32 + kt) * 16 + kh * 8 + mat * 4 + ds) * 512 + lane * 8)
                = __builtin_bit_cast(us8, pk);
        }
    } else {       // V^T fragments
        #pragma unroll
        for (int i = 0; i < 4; ++i) {
            const int c = t + i * 256;
            const int lane = c & 63, db = (c >> 6) & 3, ks = (c >> 8) & 1, kh = c >> 9;
            const int H = lane >> 5;
            const int s0 = kh * 32 + ks * 16 + H * 8;
            const int d  = db * 32 + (lane & 31);
            u32x4 pk;
            #pragma unroll
            for (int jj = 0; jj < 4; ++jj)
                pk[jj] = pk2bf(Ls[s0 + 2*jj][d], Ls[s0 + 2*jj + 1][d]);
            *(us8*)(VF + ((size_t)(kvh * 32 + kt) * 16 + kh * 8 + ks * 4 + db) * 512 + lane * 8)
                = __builtin_bit_cast(us8, pk);
        }
    }
}

// ---------- main: barrier-free streaming, register-P, global fragment loads ----------
__global__ __launch_bounds__(256, 2)
void diff_attn_mfma7(const float* __restrict__ Q,
                     const unsigned short* __restrict__ KF,
                     const unsigned short* __restrict__ VF,
                     float* __restrict__ Out)
{
    __shared__ float cb[2][32][136];   // epilogue-only combine buffer
    __shared__ float rsb[2][2][32];

    const int t   = (int)threadIdx.x;
    const int wv  = t >> 6;
    const int ln  = t & 63;
    const int mat = wv >> 1;        // 0: softmax1 (dims 0..63), 1: softmax2 (64..127)
    const int kh  = wv & 1;         // k-half of the 64-k tile
    const int q   = ln & 31;        // q-col
    const int H   = ln >> 5;

    // grid 512 = 16 h x 32 pair-slots; block does q-tiles (idx, 63-idx) sequentially
    const int bx   = (int)blockIdx.x;
    const int h    = bx & 15;
    const int idx  = bx >> 4;                 // 0..31
    const int qtA  = idx, qtB = 63 - idx;
    const int nktA = (qtA >> 1) + 1;          // nktA + nktB = 33
    const int kvh  = h >> 2;

    const unsigned short* kfb = KF + ((size_t)kvh * 32 * 16 + kh * 8 + mat * 4) * 512 + ln * 8;
    const unsigned short* vfb = VF + ((size_t)kvh * 32 * 16 + kh * 8) * 512 + ln * 8;

    const float qscale = 0.125f * 1.44269504088896340736f;  // 1/8 * log2(e)

    us8 qhi[4], qlo[4];
    auto loadQ = [&](int q0c) {
        const float* qr = Q + ((size_t)h * SEQ + q0c + q) * HEAD_DIM + mat * 64;
        #pragma unroll
        for (int ds = 0; ds < 4; ++ds) {
            const int d0 = ds * 16 + H * 8;
            float x[8];
            *(float4*)&x[0] = *(const float4*)(qr + d0);
            *(float4*)&x[4] = *(const float4*)(qr + d0 + 4);
            us8 hi8, lo8;
            #pragma unroll
            for (int j = 0; j < 8; ++j) {
                float xs = x[j] * qscale;
                unsigned short hb = f2bf(xs);
                hi8[j] = hb;
                lo8[j] = f2bf(xs - bf2f(hb));
            }
            qhi[ds] = hi8; qlo[ds] = lo8;
        }
    };

    f32x16 o[4];                   // O^T: dim = db*32+(r&3)+8*(r>>2)+4H, q-col = q
    f32x4  rsv = (f32x4)0.f;       // row-sum partials
    #pragma unroll
    for (int i = 0; i < 4; ++i) o[i] = (f32x16)0.f;

    // epilogue: combine kh halves and mats through LDS (only barriers in kernel)
    auto epilogue = [&](int q0c) {
        __syncthreads();
        float rsc = (rsv[0] + rsv[1]) + (rsv[2] + rsv[3]);
        rsc += __shfl_xor(rsc, 32, 64);
        if (ln < 32) rsb[mat][kh][ln] = rsc;
        if (kh == 1) {
            #pragma unroll
            for (int db = 0; db < 4; ++db)
                #pragma unroll
                for (int i = 0; i < 4; ++i) {
                    float4 v = { o[db][i*4+0], o[db][i*4+1], o[db][i*4+2], o[db][i*4+3] };
                    *(float4*)&cb[mat][q][db * 32 + 8 * i + 4 * H] = v;
                }
        }
        __syncthreads();
        if (kh == 0) {
            const float l = rsb[mat][0][q] + rsb[mat][1][q];
            const float a = mat ? (0.16f / l) : (0.2f / l);
            #pragma unroll
            for (int db = 0; db < 4; ++db)
                #pragma unroll
                for (int i = 0; i < 4; ++i) {
                    float4 v = *(float4*)&cb[mat][q][db * 32 + 8 * i + 4 * H];
                    o[db][i*4+0] = (o[db][i*4+0] + v.x) * a;
                    o[db][i*4+1] = (o[db][i*4+1] + v.y) * a;
                    o[db][i*4+2] = (o[db][i*4+2] + v.z) * a;
                    o[db][i*4+3] = (o[db][i*4+3] + v.w) * a;
                }
            if (mat == 1) {
                #pragma unroll
                for (int db = 0; db < 4; ++db)
                    #pragma unroll
                    for (int i = 0; i < 4; ++i) {
                        float4 v = { o[db][i*4+0], o[db][i*4+1], o[db][i*4+2], o[db][i*4+3] };
                        *(float4*)&cb[1][q][db * 32 + 8 * i + 4 * H] = v;
                    }
            }
        }
        __syncthreads();
        if (wv == 0) {
            float* ob = Out + ((size_t)h * SEQ + q0c + q) * HEAD_DIM;
            #pragma unroll
            for (int db = 0; db < 4; ++db)
                #pragma unroll
                for (int i = 0; i < 4; ++i) {
                    float4 v = *(float4*)&cb[1][q][db * 32 + 8 * i + 4 * H];
                    float4 r;
                    r.x = o[db][i*4+0] - v.x;
                    r.y = o[db][i*4+1] - v.y;
                    r.z = o[db][i*4+2] - v.z;
                    r.w = o[db][i*4+3] - v.w;
                    *(float4*)(ob + db * 32 + 8 * i + 4 * H) = r;
                }
        }
    };

    int q0 = qtA * 32, qpar = qtA & 1;
    loadQ(q0);

    us8 ka[4], kan[4], va[8];
    #pragma unroll
    for (int ds = 0; ds < 4; ++ds) ka[ds] = *(const us8*)(kfb + ds * 512);

    for (int j = 0; j < 33; ++j) {
        if (j == nktA) {                       // q-tile boundary
            epilogue(q0);
            q0 = qtB * 32; qpar = qtB & 1;
            loadQ(q0);
            #pragma unroll
            for (int i = 0; i < 4; ++i) o[i] = (f32x16)0.f;
            rsv = (f32x4)0.f;
        }
        const int kt = (j < nktA) ? j : j - nktA;

        // V frags for THIS iter (consumed in PV, ~400 cyc later)
        {
            const unsigned short* vb = vfb + (size_t)kt * KT_STRIDE;
            #pragma unroll
            for (int c = 0; c < 8; ++c) va[c] = *(const us8*)(vb + c * 512);
        }
        // K frags prefetch for NEXT iter (full iteration of latency cover)
        if (j + 1 < 33) {
            const int nk = (j + 1 >= nktA) ? (j + 1 - nktA) : (j + 1);
            const unsigned short* kb = kfb + (size_t)nk * KT_STRIDE;
            #pragma unroll
            for (int ds = 0; ds < 4; ++ds) kan[ds] = *(const us8*)(kb + ds * 512);
        }

        const bool diag  = (j == nktA - 1) || (j == 32);
        const bool skipw = diag && (qpar == 0) && (kh == 1);   // fully-masked half
        const bool triw  = diag && (kh == qpar);               // triangular half

        if (!skipw) {
            // ---- scores S^T[k][q] = K . Q^T ----
            f32x16 s = (f32x16)0.f;
            #pragma unroll
            for (int ds = 0; ds < 4; ++ds) {
                s = mfma32(ka[ds], qhi[ds], s);
                s = mfma32(ka[ds], qlo[ds], s);
            }
            // ---- exp2 + truncate to bf16 (denominator from quantized P) ----
            unsigned c[16];
            if (triw) {
                const int kg0 = kt * 64 + kh * 32 + 4 * H;
                const int qg  = q0 + q;
                #pragma unroll
                for (int r = 0; r < 16; ++r) {
                    const int kg = kg0 + (r & 3) + ((r >> 2) << 3);
                    float e = (kg <= qg) ? fast_exp2(s[r]) : 0.f;
                    c[r] = __builtin_bit_cast(unsigned, e) & 0xffff0000u;
                    rsv[r & 3] += __builtin_bit_cast(float, c[r]);
                }
            } else {
                #pragma unroll
                for (int r = 0; r < 16; ++r) {
                    float e = fast_exp2(s[r]);
                    c[r] = __builtin_bit_cast(unsigned, e) & 0xffff0000u;
                    rsv[r & 3] += __builtin_bit_cast(float, c[r]);
                }
            }
            // ---- P C-frag -> B-frag in registers (lane^32 swap), then PV ----
            #pragma unroll
            for (int ks = 0; ks < 2; ++ks) {
                const unsigned pA = (c[8*ks+0] >> 16) | c[8*ks+1];
                const unsigned pB = (c[8*ks+2] >> 16) | c[8*ks+3];
                const unsigned pC = (c[8*ks+4] >> 16) | c[8*ks+5];
                const unsigned pD = (c[8*ks+6] >> 16) | c[8*ks+7];
                const unsigned x1 = H ? pA : pC;
                const unsigned x2 = H ? pB : pD;
                const unsigned t1 = (unsigned)__shfl_xor((int)x1, 32, 64);
                const unsigned t2 = (unsigned)__shfl_xor((int)x2, 32, 64);
                u32x4 bw;
                bw[0] = H ? t1 : pA;
                bw[1] = H ? t2 : pB;
                bw[2] = H ? pC : t1;
                bw[3] = H ? pD : t2;
                const us8 bp = __builtin_bit_cast(us8, bw);
                #pragma unroll
                for (int db = 0; db < 4; ++db)
                    o[db] = mfma32(va[ks * 4 + db], bp, o[db]);
            }
        }

        #pragma unroll
        for (int ds = 0; ds < 4; ++ds) ka[ds] = kan[ds];
    }

    epilogue(q0);
}

extern "C" void kernel_launch(void* const* d_in, const int* in_sizes, int n_in,
                              void* d_out, int out_size, void* d_ws, size_t ws_size,
                              hipStream_t stream) {
    const float* Q = (const float*)d_in[0];
    const float* K = (const float*)d_in[1];
    const float* V = (const float*)d_in[2];
    float* Out = (float*)d_out;

    unsigned short* KF = (unsigned short*)d_ws;             // 2 MB
    unsigned short* VF = KF + (size_t)4 * SEQ * HEAD_DIM;   // 2 MB

    prep_frag<<<256, 256, 0, stream>>>(K, V, KF, VF);
    diff_attn_mfma7<<<512, 256, 0, stream>>>(Q, KF, VF, Out);
}